// Round 8
// baseline (533.677 us; speedup 1.0000x reference)
//
#include <hip/hip_runtime.h>

#define N_NODES 50000
#define N_EDGES 800000
#define N_GRAPHS 2048
#define IN_DIM 128
#define HID 256
#define N_LAYERS 4
#define BN_EPS 1e-5f
#define NBIN 128
#define WSCALE 64.0f

#define EDGE_BLKS 3125   // ceil(800000/256)
#define NODE_BLKS 196    // ceil(50000/256)

typedef unsigned short ushort_t;
typedef float f32x4 __attribute__((ext_vector_type(4)));
typedef unsigned int u32x4 __attribute__((ext_vector_type(4)));
typedef _Float16 f16x8 __attribute__((ext_vector_type(8)));
typedef _Float16 f16x4 __attribute__((ext_vector_type(4)));

// ---- async global->LDS, 16B per lane ----
__device__ __forceinline__ void gl_lds16(const ushort_t* g, ushort_t* l) {
    __builtin_amdgcn_global_load_lds(
        (const __attribute__((address_space(1))) void*)g,
        (__attribute__((address_space(3))) void*)l, 16, 0, 0);
}

// ---------------- degree count + graph bounds (independent work, fused grid) ----------------
__global__ __launch_bounds__(256) void k_degbounds(const int* __restrict__ dst,
                                                   int* __restrict__ degi,
                                                   const int* __restrict__ batch,
                                                   int* __restrict__ gstart,
                                                   int* __restrict__ gend) {
    int bid = blockIdx.x;
    if (bid < EDGE_BLKS) {
        int e = bid * 256 + threadIdx.x;
        if (e < N_EDGES) atomicAdd(&degi[dst[e]], 1);
    } else {
        int n = (bid - EDGE_BLKS) * 256 + threadIdx.x;
        if (n >= N_NODES) return;
        int g = batch[n];
        if (n == 0 || batch[n - 1] != g) gstart[g] = n;
        if (n == N_NODES - 1 || batch[n + 1] != g) gend[g] = n + 1;
    }
}

// ---------------- node norms + degree histogram (fused, hierarchical) ----------------
__global__ __launch_bounds__(256) void k_nodeprep(const int* __restrict__ degi,
                                                  float* __restrict__ dinv,
                                                  float* __restrict__ selfn,
                                                  int* __restrict__ bins, int N) {
    __shared__ int lbin[NBIN];
    int t = threadIdx.x;
    if (t < NBIN) lbin[t] = 0;
    __syncthreads();
    int n = blockIdx.x * 256 + t;
    if (n < N) {
        int dg = degi[n];
        float d = 1.0f + (float)dg;
        dinv[n] = 1.0f / sqrtf(d);
        selfn[n] = 1.0f / d;
        atomicAdd(&lbin[min(dg, NBIN - 1)], 1);
    }
    __syncthreads();
    if (t < NBIN && lbin[t] > 0) atomicAdd(&bins[t], lbin[t]);
}

// ---------------- bin prefix (one wave, shfl scan over 128 bins) ----------------
__global__ void k_binscan(const int* __restrict__ bins, int* __restrict__ binstart,
                          int* __restrict__ bincur, int* __restrict__ edgebase) {
    int t = threadIdx.x & 63;
    int d0 = 2 * t, d1 = 2 * t + 1;
    int a = bins[d0], b = bins[d1];
    int ea = a * d0, eb = b * d1;
    int s = a + b, es = ea + eb;
    int ps = s, pe = es;
    #pragma unroll
    for (int off = 1; off < 64; off <<= 1) {
        int u = __shfl_up(ps, off, 64);
        int v = __shfl_up(pe, off, 64);
        if (t >= off) { ps += u; pe += v; }
    }
    int exs = ps - s, exe = pe - es;
    binstart[d0] = exs;     bincur[d0] = exs;     edgebase[d0] = exe;
    binstart[d1] = exs + a; bincur[d1] = exs + a; edgebase[d1] = exe + ea;
}

// ---------------- parallel slot assignment; emits per-slot meta + per-NODE fill meta ----------
// invmeta[n] = {edata_base, stride, bits(dinv[n]), 0}; cursor node-indexed (R7 win).
__global__ __launch_bounds__(256) void k_assign(const int* __restrict__ degi,
                                                const int* __restrict__ binstart,
                                                const int* __restrict__ edgebase,
                                                const int* __restrict__ bins,
                                                int* __restrict__ bincur,
                                                const float* __restrict__ dinv,
                                                int* __restrict__ perm,
                                                int4* __restrict__ invmeta,
                                                int2* __restrict__ meta, int* __restrict__ cursor,
                                                int N) {
    __shared__ int lbin[NBIN];
    __shared__ int lbase[NBIN];
    int t = threadIdx.x;
    if (t < NBIN) lbin[t] = 0;
    __syncthreads();
    int n = blockIdx.x * 256 + t;
    int d = 0, lrank = 0;
    if (n < N) {
        d = min(degi[n], NBIN - 1);
        lrank = atomicAdd(&lbin[d], 1);
    }
    __syncthreads();
    if (t < NBIN && lbin[t] > 0) lbase[t] = atomicAdd(&bincur[t], lbin[t]);
    __syncthreads();
    if (n < N) {
        int slot = lbase[d] + lrank;
        int base = edgebase[d] + (slot - binstart[d]);
        perm[slot] = n;
        int2 m;
        m.x = base;
        m.y = bins[d] | (d << 20);
        meta[slot] = m;
        int4 im;
        im.x = base;
        im.y = bins[d];
        im.z = __float_as_int(dinv[n]);
        im.w = 0;
        invmeta[n] = im;
        cursor[n] = 0;
    }
}

// ---------------- fused: CSR fill (short-chain scatter) + prep (streaming) ----------------
// Fill at its scatter floor (R6: partitioning loses; R7: chain 4->3 got 50->46us).
// record = (fp16(dinv[s]*dinv[d]) << 16) | src   (src < 65536 fits 16 bits)
__global__ __launch_bounds__(256) void k_fillprep(const int* __restrict__ src,
                                                  const int* __restrict__ dst,
                                                  const float* __restrict__ dinv,
                                                  const int4* __restrict__ invmeta,
                                                  int* __restrict__ cursor,
                                                  unsigned int* __restrict__ edata,
                                                  const float* __restrict__ gamma,
                                                  const float* __restrict__ beta,
                                                  const float* __restrict__ mean,
                                                  const float* __restrict__ var,
                                                  const float* __restrict__ bias,
                                                  const float* __restrict__ W0,
                                                  const float* __restrict__ Ws,
                                                  const float* __restrict__ x,
                                                  float* __restrict__ scale,
                                                  float* __restrict__ shift,
                                                  _Float16* __restrict__ Wh,
                                                  _Float16* __restrict__ Wl,
                                                  _Float16* __restrict__ X16) {
    int bid = blockIdx.x;
    if (bid < EDGE_BLKS) {
        int e = bid * 256 + threadIdx.x;
        if (e >= N_EDGES) return;
        int s = src[e], d = dst[e];
        int4 im = invmeta[d];               // base | stride | dinv[d]
        int j = atomicAdd(&cursor[d], 1);   // depends only on dst
        float wdd = __int_as_float(im.z);
        float wss = dinv[s];
        int pos = im.x + j * im.y;
        _Float16 hw = (_Float16)(wss * wdd);     // RTN
        edata[pos] = ((unsigned int)__builtin_bit_cast(unsigned short, hw) << 16) |
                     (unsigned int)s;
        return;
    }
    int id = (bid - EDGE_BLKS) * 256 + threadIdx.x;
    if (id < N_LAYERS * HID) {
        float s = gamma[id] * rsqrtf(var[id] + BN_EPS);
        scale[id] = s / WSCALE;
        shift[id] = beta[id] + (bias[id] - mean[id]) * s;
        return;
    }
    id -= N_LAYERS * HID;
    const int WT = 128 * 256 + 3 * 256 * 256;
    if (id < WT) {
        float v;
        if (id < 32768) {
            int n = id >> 7, k = id & 127;
            v = W0[k * 256 + n];
        } else {
            int t = id - 32768;
            int l = t >> 16;
            int r = t & 65535;
            int n = r >> 8, k = r & 255;
            v = Ws[l * 65536 + k * 256 + n];
        }
        v *= WSCALE;
        _Float16 h = (_Float16)v;
        Wh[id] = h;
        Wl[id] = (_Float16)(v - (float)h);
        return;
    }
    id -= WT;
    const int total4 = N_NODES * IN_DIM / 4;
    if (id < total4) {
        float4 v = ((const float4*)x)[id];
        int n = id >> 5;
        int c0 = (id & 31) * 4;
        f16x4 o;
        o.x = (_Float16)v.x; o.y = (_Float16)v.y; o.z = (_Float16)v.z; o.w = (_Float16)v.w;
        *(f16x4*)(X16 + (size_t)(c0 >> 5) * (N_NODES * 32) + (size_t)n * 32 + (c0 & 31)) = o;
    }
}

// ---------------- MFMA fp16 2-term GEMM + fused BN/ReLU epilogue (fp16 out) ----------------
__global__ __launch_bounds__(256) void k_gemm(const _Float16* __restrict__ A,
                                              const _Float16* __restrict__ Wh,
                                              const _Float16* __restrict__ Wl,
                                              const float* __restrict__ bnscale,
                                              const float* __restrict__ bnshift,
                                              _Float16* __restrict__ X16, int K) {
    __shared__ _Float16 sm[3 * 128 * 32]; // 24 KB: A | Wh | Wl tiles
    _Float16* tA  = sm;
    _Float16* tWh = sm + 4096;
    _Float16* tWl = sm + 8192;

    int tid = threadIdx.x;
    int lane = tid & 63;
    int w = tid >> 6;
    int wrow = w & 1, wcol = w >> 1;
    int row0 = blockIdx.x * 128;
    int col0 = blockIdx.y * 128;

    int srow = lane >> 2;
    int sch = lane & 3;

    f32x4 acc[4][4] = {};
    int m = lane & 15, q = lane >> 4;

    for (int k0 = 0; k0 < K; k0 += 32) {
        #pragma unroll
        for (int ii = 0; ii < 6; ++ii) {
            int G = w * 6 + ii;       // 0..23
            int mat = G >> 3;         // 0=A, 1=Wh, 2=Wl
            int grp = G & 7;
            const _Float16* gs = (mat == 0) ? A : (mat == 1) ? Wh : Wl;
            _Float16* ld = sm + mat * 4096;
            int rb = (mat == 0) ? row0 : col0;
            int rl = (mat == 0) ? N_NODES : (col0 + 128);
            int r = grp * 16 + srow;
            int grow = rb + r;
            int gch = sch ^ (r & 3);
            if (grow < rl)
                gl_lds16((const ushort_t*)(gs + (size_t)grow * K + k0 + gch * 8),
                         (ushort_t*)(ld + grp * 512));
        }
        __syncthreads();

        f16x8 af[4], whf[4], wlf[4];
        #pragma unroll
        for (int r = 0; r < 4; ++r) {
            int rr = wrow * 64 + r * 16 + m;
            int off = rr * 32 + ((q ^ (rr & 3)) << 3);
            af[r] = *(const f16x8*)(tA + off);
        }
        #pragma unroll
        for (int c = 0; c < 4; ++c) {
            int nn = wcol * 64 + c * 16 + m;
            int off = nn * 32 + ((q ^ (nn & 3)) << 3);
            whf[c] = *(const f16x8*)(tWh + off);
            wlf[c] = *(const f16x8*)(tWl + off);
        }
        #pragma unroll
        for (int r = 0; r < 4; ++r)
            #pragma unroll
            for (int c = 0; c < 4; ++c) {
                acc[r][c] = __builtin_amdgcn_mfma_f32_16x16x32_f16(af[r], whf[c], acc[r][c], 0, 0, 0);
                acc[r][c] = __builtin_amdgcn_mfma_f32_16x16x32_f16(af[r], wlf[c], acc[r][c], 0, 0, 0);
            }
        __syncthreads();
    }

    #pragma unroll
    for (int r = 0; r < 4; ++r) {
        int mrow = row0 + wrow * 64 + r * 16 + (lane >> 4) * 4;
        #pragma unroll
        for (int c = 0; c < 4; ++c) {
            int n = col0 + wcol * 64 + c * 16 + (lane & 15);
            float sc = bnscale[n];
            float sh = bnshift[n];
            f32x4 v = acc[r][c];
            _Float16* base = X16 + (size_t)(n >> 5) * (N_NODES * 32) + (n & 31);
            #pragma unroll
            for (int g = 0; g < 4; ++g)
                if (mrow + g < N_NODES)
                    base[(size_t)(mrow + g) * 32] =
                        (_Float16)fmaxf(fmaf(v[g], sc, sh), 0.f);
        }
    }
}

// ---------------- chunked gather on fp16 X: Âx -> fp16 A node-major ----------------
// TWO chunks per block: each edge record is loaded once per chunk-PAIR (halves the
// 8x edata re-stream) and feeds two independent 16B feature loads (2x load MLP per
// edata round-trip). Longest-work-first nb (R4 win); edata loads PLAIN (R1 lesson).
#define GNB 782  // ceil(50000/64) slot-blocks per chunk-group

__global__ __launch_bounds__(256) void k_gather(const _Float16* __restrict__ Xc,
                                                const int2* __restrict__ meta,
                                                const unsigned int* __restrict__ edata,
                                                const int* __restrict__ perm,
                                                const float* __restrict__ selfn,
                                                _Float16* __restrict__ A,
                                                int K, int gshift) {
    int bid = blockIdx.x;
    int cg = bid & ((1 << gshift) - 1);       // chunk-group (2 chunks)
    int nb = (GNB - 1) - (bid >> gshift);     // longest-work-first
    const _Float16* Hc0 = Xc + (size_t)(cg * 2)     * (N_NODES * 32);
    const _Float16* Hc1 = Xc + (size_t)(cg * 2 + 1) * (N_NODES * 32);
    int slot = nb * 64 + (threadIdx.x >> 2);
    if (slot >= N_NODES) return;
    int node = perm[slot];
    int2 m = meta[slot];
    int q8 = (threadIdx.x & 3) * 8;

    int stride = m.y & 0xFFFFF;
    int deg = m.y >> 20;
    const unsigned int* ep = edata + m.x;
    float sn = selfn[node];

    float acc0[8], acc1[8];
    {
        f16x8 h0 = *(const f16x8*)(Hc0 + (size_t)node * 32 + q8);
        f16x8 h1 = *(const f16x8*)(Hc1 + (size_t)node * 32 + q8);
        #pragma unroll
        for (int i = 0; i < 8; ++i) { acc0[i] = (float)h0[i] * sn; acc1[i] = (float)h1[i] * sn; }
    }

    int j = 0;
    for (; j + 7 < deg; j += 8) {
        unsigned int e[8];
        #pragma unroll
        for (int i = 0; i < 8; ++i)
            e[i] = ep[(size_t)(j + i) * stride];
        // two sub-batches of 4 edges: 8 feature loads in flight each, caps VGPR
        #pragma unroll
        for (int h = 0; h < 2; ++h) {
            f16x8 a0[4], a1[4];
            #pragma unroll
            for (int i = 0; i < 4; ++i) {
                size_t off = (size_t)(e[h * 4 + i] & 0xFFFFu) * 32 + q8;
                a0[i] = *(const f16x8*)(Hc0 + off);
                a1[i] = *(const f16x8*)(Hc1 + off);
            }
            #pragma unroll
            for (int i = 0; i < 4; ++i) {
                float w = (float)__builtin_bit_cast(_Float16,
                              (unsigned short)(e[h * 4 + i] >> 16));
                #pragma unroll
                for (int c = 0; c < 8; ++c) {
                    acc0[c] = fmaf((float)a0[i][c], w, acc0[c]);
                    acc1[c] = fmaf((float)a1[i][c], w, acc1[c]);
                }
            }
        }
    }
    if (j + 3 < deg) {
        unsigned int e[4];
        #pragma unroll
        for (int i = 0; i < 4; ++i)
            e[i] = ep[(size_t)(j + i) * stride];
        f16x8 a0[4], a1[4];
        #pragma unroll
        for (int i = 0; i < 4; ++i) {
            size_t off = (size_t)(e[i] & 0xFFFFu) * 32 + q8;
            a0[i] = *(const f16x8*)(Hc0 + off);
            a1[i] = *(const f16x8*)(Hc1 + off);
        }
        #pragma unroll
        for (int i = 0; i < 4; ++i) {
            float w = (float)__builtin_bit_cast(_Float16, (unsigned short)(e[i] >> 16));
            #pragma unroll
            for (int c = 0; c < 8; ++c) {
                acc0[c] = fmaf((float)a0[i][c], w, acc0[c]);
                acc1[c] = fmaf((float)a1[i][c], w, acc1[c]);
            }
        }
        j += 4;
    }
    for (; j < deg; ++j) {
        unsigned int e0 = ep[(size_t)j * stride];
        size_t off = (size_t)(e0 & 0xFFFFu) * 32 + q8;
        f16x8 a0 = *(const f16x8*)(Hc0 + off);
        f16x8 a1 = *(const f16x8*)(Hc1 + off);
        float w0 = (float)__builtin_bit_cast(_Float16, (unsigned short)(e0 >> 16));
        #pragma unroll
        for (int i = 0; i < 8; ++i) {
            acc0[i] = fmaf((float)a0[i], w0, acc0[i]);
            acc1[i] = fmaf((float)a1[i], w0, acc1[i]);
        }
    }

    f16x8 o0, o1;
    #pragma unroll
    for (int i = 0; i < 8; ++i) { o0[i] = (_Float16)acc0[i]; o1[i] = (_Float16)acc1[i]; }
    _Float16* ab = A + (size_t)node * K + cg * 64 + q8;
    __builtin_nontemporal_store(*(u32x4*)&o0, (u32x4*)ab);
    __builtin_nontemporal_store(*(u32x4*)&o1, (u32x4*)(ab + 32));
}

// ---------------- fused mean-pool + MLP head (one block per graph) ----------------
__global__ __launch_bounds__(128) void k_poolmlp(const _Float16* __restrict__ X16,
                                                 const int* __restrict__ gstart,
                                                 const int* __restrict__ gend,
                                                 const float* __restrict__ W1,
                                                 const float* __restrict__ b1,
                                                 const float* __restrict__ W2,
                                                 const float* __restrict__ b2,
                                                 float* __restrict__ out) {
    __shared__ float prow[HID];
    __shared__ float hred[2];
    int g = blockIdx.x;
    int s = gstart[g], e = gend[g];
    int j = threadIdx.x; // 0..127, channels j and j+128
    const _Float16* p0 = X16 + (size_t)(j >> 5) * (N_NODES * 32) + (j & 31);
    const _Float16* p1 = X16 + (size_t)((j >> 5) + 4) * (N_NODES * 32) + (j & 31);
    float a0 = 0.f, a1 = 0.f;
    for (int n = s; n < e; ++n) {
        a0 += (float)p0[(size_t)n * 32];
        a1 += (float)p1[(size_t)n * 32];
    }
    float inv = 1.0f / fmaxf((float)(e - s), 1.0f);
    prow[j] = a0 * inv;
    prow[j + 128] = a1 * inv;
    __syncthreads();
    float acc = 0.f;
    #pragma unroll 8
    for (int k = 0; k < HID; ++k) acc += prow[k] * W1[k * 128 + j];
    float h = fmaxf(acc + b1[j], 0.f);
    float p = h * W2[j];
    #pragma unroll
    for (int off = 32; off > 0; off >>= 1) p += __shfl_down(p, off, 64);
    if ((j & 63) == 0) hred[j >> 6] = p;
    __syncthreads();
    if (j == 0) out[g] = hred[0] + hred[1] + b2[0];
}

extern "C" void kernel_launch(void* const* d_in, const int* in_sizes, int n_in,
                              void* d_out, int out_size, void* d_ws, size_t ws_size,
                              hipStream_t stream) {
    const float* x      = (const float*)d_in[0];
    const int*   ei     = (const int*)d_in[1];
    const int*   batch  = (const int*)d_in[2];
    const float* convW0 = (const float*)d_in[3];
    const float* convWs = (const float*)d_in[4];
    const float* convB  = (const float*)d_in[5];
    const float* gamma  = (const float*)d_in[6];
    const float* beta   = (const float*)d_in[7];
    const float* mean   = (const float*)d_in[8];
    const float* var    = (const float*)d_in[9];
    const float* lin1W  = (const float*)d_in[10];
    const float* lin1b  = (const float*)d_in[11];
    const float* lin2W  = (const float*)d_in[12];
    const float* lin2b  = (const float*)d_in[13];
    float* out = (float*)d_out;

    const int* src = ei;
    const int* dst = ei + N_EDGES;

    const int WTOT = 128 * 256 + 3 * 256 * 256; // 229376

    char* wsb = (char*)d_ws;
    _Float16* x16a = (_Float16*)wsb;                     // N*HID fp16 (ping)
    _Float16* x16b = x16a + (size_t)N_NODES * HID;       // N*HID fp16 (pong)
    _Float16* Ab   = x16b + (size_t)N_NODES * HID;       // N*HID fp16 (GEMM A operand)
    _Float16* Wh16 = Ab + (size_t)N_NODES * HID;         // WTOT fp16
    _Float16* Wl16 = Wh16 + WTOT;                        // WTOT fp16
    float* dinv    = (float*)(Wl16 + WTOT);              // N
    float* selfn   = dinv + N_NODES;                     // N
    float* bnscale = selfn + N_NODES;                    // 4*HID
    float* bnshift = bnscale + N_LAYERS * HID;           // 4*HID
    // contiguous zero-init region: degi | bins | gstart | gend
    int*   degi    = (int*)(bnshift + N_LAYERS * HID);   // N
    int*   bins    = degi + N_NODES;                     // NBIN
    int*   gstart  = bins + NBIN;                        // G
    int*   gend    = gstart + N_GRAPHS;                  // G
    int*   binstart= gend + N_GRAPHS;                    // NBIN
    int*   bincur  = binstart + NBIN;                    // NBIN
    int*   edgebase= bincur + NBIN;                      // NBIN
    int*   cursor  = edgebase + NBIN;                    // N (node-indexed)
    int*   perm    = cursor + N_NODES;                   // N
    int2*  meta    = (int2*)(perm + N_NODES);            // N int2
    int4*  invmeta = (int4*)(meta + N_NODES);            // N int4 (per-node fill meta)
    unsigned int* edata = (unsigned int*)(invmeta + N_NODES); // E u32 (packed)

    hipMemsetAsync(degi, 0, (size_t)(N_NODES + NBIN + 2 * N_GRAPHS) * 4, stream);

    // CSR build + norms + degree sort (all parallel; closed-form offsets)
    k_degbounds<<<EDGE_BLKS + NODE_BLKS, 256, 0, stream>>>(dst, degi, batch, gstart, gend);
    k_nodeprep<<<NODE_BLKS, 256, 0, stream>>>(degi, dinv, selfn, bins, N_NODES);
    k_binscan<<<1, 64, 0, stream>>>(bins, binstart, bincur, edgebase);
    k_assign<<<NODE_BLKS, 256, 0, stream>>>(degi, binstart, edgebase, bins, bincur, dinv,
                                            perm, invmeta, meta, cursor, N_NODES);

    // fused: CSR fill (short-chain) + prep (streaming)
    const int PREP_TOT = N_LAYERS * HID + WTOT + N_NODES * IN_DIM / 4;
    const int PREP_BLKS = (PREP_TOT + 255) / 256;
    k_fillprep<<<EDGE_BLKS + PREP_BLKS, 256, 0, stream>>>(src, dst, dinv, invmeta,
                                                          cursor, edata,
                                                          gamma, beta, mean, var, convB,
                                                          convW0, convWs, x,
                                                          bnscale, bnshift, Wh16, Wl16, x16a);

    // layers: gather (Âx, fp16, 2 chunks/block) -> fp16 2-term GEMM (+BN+ReLU, fp16 out)
    dim3 gg((N_NODES + 127) / 128, 2);
    _Float16* cur = x16a;
    for (int l = 0; l < N_LAYERS; ++l) {
        int K = (l == 0) ? IN_DIM : HID;
        int ngroups = K / 64;                  // chunk-pairs
        int gshift = (l == 0) ? 1 : 2;
        size_t woff = (l == 0) ? 0 : (size_t)(32768 + (l - 1) * 65536);
        k_gather<<<ngroups * GNB, 256, 0, stream>>>(cur, meta, edata, perm, selfn,
                                                    Ab, K, gshift);
        _Float16* nxt = (cur == x16a) ? x16b : x16a;
        k_gemm<<<gg, 256, 0, stream>>>(Ab, Wh16 + woff, Wl16 + woff,
                                       bnscale + l * HID, bnshift + l * HID, nxt, K);
        cur = nxt;
    }

    k_poolmlp<<<N_GRAPHS, 128, 0, stream>>>(cur, gstart, gend, lin1W, lin1b, lin2W, lin2b, out);
}

// Round 9
// 475.591 us; speedup vs baseline: 1.1221x; 1.1221x over previous
//
#include <hip/hip_runtime.h>

#define N_NODES 50000
#define N_EDGES 800000
#define N_GRAPHS 2048
#define IN_DIM 128
#define HID 256
#define N_LAYERS 4
#define BN_EPS 1e-5f
#define NBIN 128
#define WSCALE 64.0f

#define EDGE_BLKS 3125   // ceil(800000/256)
#define NODE_BLKS 196    // ceil(50000/256)

typedef unsigned short ushort_t;
typedef float f32x4 __attribute__((ext_vector_type(4)));
typedef unsigned int u32x4 __attribute__((ext_vector_type(4)));
typedef _Float16 f16x8 __attribute__((ext_vector_type(8)));
typedef _Float16 f16x4 __attribute__((ext_vector_type(4)));

// ---- async global->LDS, 16B per lane ----
__device__ __forceinline__ void gl_lds16(const ushort_t* g, ushort_t* l) {
    __builtin_amdgcn_global_load_lds(
        (const __attribute__((address_space(1))) void*)g,
        (__attribute__((address_space(3))) void*)l, 16, 0, 0);
}

// ---------------- degree count + graph bounds (independent work, fused grid) ----------------
__global__ __launch_bounds__(256) void k_degbounds(const int* __restrict__ dst,
                                                   int* __restrict__ degi,
                                                   const int* __restrict__ batch,
                                                   int* __restrict__ gstart,
                                                   int* __restrict__ gend) {
    int bid = blockIdx.x;
    if (bid < EDGE_BLKS) {
        int e = bid * 256 + threadIdx.x;
        if (e < N_EDGES) atomicAdd(&degi[dst[e]], 1);
    } else {
        int n = (bid - EDGE_BLKS) * 256 + threadIdx.x;
        if (n >= N_NODES) return;
        int g = batch[n];
        if (n == 0 || batch[n - 1] != g) gstart[g] = n;
        if (n == N_NODES - 1 || batch[n + 1] != g) gend[g] = n + 1;
    }
}

// ---------------- node norms + degree histogram (fused, hierarchical) ----------------
__global__ __launch_bounds__(256) void k_nodeprep(const int* __restrict__ degi,
                                                  float* __restrict__ dinv,
                                                  float* __restrict__ selfn,
                                                  int* __restrict__ bins, int N) {
    __shared__ int lbin[NBIN];
    int t = threadIdx.x;
    if (t < NBIN) lbin[t] = 0;
    __syncthreads();
    int n = blockIdx.x * 256 + t;
    if (n < N) {
        int dg = degi[n];
        float d = 1.0f + (float)dg;
        dinv[n] = 1.0f / sqrtf(d);
        selfn[n] = 1.0f / d;
        atomicAdd(&lbin[min(dg, NBIN - 1)], 1);
    }
    __syncthreads();
    if (t < NBIN && lbin[t] > 0) atomicAdd(&bins[t], lbin[t]);
}

// ---------------- bin prefix (one wave, shfl scan over 128 bins) ----------------
__global__ void k_binscan(const int* __restrict__ bins, int* __restrict__ binstart,
                          int* __restrict__ bincur, int* __restrict__ edgebase) {
    int t = threadIdx.x & 63;
    int d0 = 2 * t, d1 = 2 * t + 1;
    int a = bins[d0], b = bins[d1];
    int ea = a * d0, eb = b * d1;
    int s = a + b, es = ea + eb;
    int ps = s, pe = es;
    #pragma unroll
    for (int off = 1; off < 64; off <<= 1) {
        int u = __shfl_up(ps, off, 64);
        int v = __shfl_up(pe, off, 64);
        if (t >= off) { ps += u; pe += v; }
    }
    int exs = ps - s, exe = pe - es;
    binstart[d0] = exs;     bincur[d0] = exs;     edgebase[d0] = exe;
    binstart[d1] = exs + a; bincur[d1] = exs + a; edgebase[d1] = exe + ea;
}

// ---------------- parallel slot assignment; emits per-slot meta + per-NODE fill meta ----------
// invmeta[n] = {edata_base, stride, bits(dinv[n]), 0}; cursor node-indexed (R7 win).
__global__ __launch_bounds__(256) void k_assign(const int* __restrict__ degi,
                                                const int* __restrict__ binstart,
                                                const int* __restrict__ edgebase,
                                                const int* __restrict__ bins,
                                                int* __restrict__ bincur,
                                                const float* __restrict__ dinv,
                                                int* __restrict__ perm,
                                                int4* __restrict__ invmeta,
                                                int2* __restrict__ meta, int* __restrict__ cursor,
                                                int N) {
    __shared__ int lbin[NBIN];
    __shared__ int lbase[NBIN];
    int t = threadIdx.x;
    if (t < NBIN) lbin[t] = 0;
    __syncthreads();
    int n = blockIdx.x * 256 + t;
    int d = 0, lrank = 0;
    if (n < N) {
        d = min(degi[n], NBIN - 1);
        lrank = atomicAdd(&lbin[d], 1);
    }
    __syncthreads();
    if (t < NBIN && lbin[t] > 0) lbase[t] = atomicAdd(&bincur[t], lbin[t]);
    __syncthreads();
    if (n < N) {
        int slot = lbase[d] + lrank;
        int base = edgebase[d] + (slot - binstart[d]);
        perm[slot] = n;
        int2 m;
        m.x = base;
        m.y = bins[d] | (d << 20);
        meta[slot] = m;
        int4 im;
        im.x = base;
        im.y = bins[d];
        im.z = __float_as_int(dinv[n]);
        im.w = 0;
        invmeta[n] = im;
        cursor[n] = 0;
    }
}

// ---------------- fused: CSR fill (short-chain scatter) + prep (streaming) ----------------
// Fill at its scatter floor (R6: partitioning loses; R7: chain 4->3 got 50->46us).
// record = (fp16(dinv[s]*dinv[d]) << 16) | src   (src < 65536 fits 16 bits)
__global__ __launch_bounds__(256) void k_fillprep(const int* __restrict__ src,
                                                  const int* __restrict__ dst,
                                                  const float* __restrict__ dinv,
                                                  const int4* __restrict__ invmeta,
                                                  int* __restrict__ cursor,
                                                  unsigned int* __restrict__ edata,
                                                  const float* __restrict__ gamma,
                                                  const float* __restrict__ beta,
                                                  const float* __restrict__ mean,
                                                  const float* __restrict__ var,
                                                  const float* __restrict__ bias,
                                                  const float* __restrict__ W0,
                                                  const float* __restrict__ Ws,
                                                  const float* __restrict__ x,
                                                  float* __restrict__ scale,
                                                  float* __restrict__ shift,
                                                  _Float16* __restrict__ Wh,
                                                  _Float16* __restrict__ Wl,
                                                  _Float16* __restrict__ X16) {
    int bid = blockIdx.x;
    if (bid < EDGE_BLKS) {
        int e = bid * 256 + threadIdx.x;
        if (e >= N_EDGES) return;
        int s = src[e], d = dst[e];
        int4 im = invmeta[d];               // base | stride | dinv[d]
        int j = atomicAdd(&cursor[d], 1);   // depends only on dst
        float wdd = __int_as_float(im.z);
        float wss = dinv[s];
        int pos = im.x + j * im.y;
        _Float16 hw = (_Float16)(wss * wdd);     // RTN
        edata[pos] = ((unsigned int)__builtin_bit_cast(unsigned short, hw) << 16) |
                     (unsigned int)s;
        return;
    }
    int id = (bid - EDGE_BLKS) * 256 + threadIdx.x;
    if (id < N_LAYERS * HID) {
        float s = gamma[id] * rsqrtf(var[id] + BN_EPS);
        scale[id] = s / WSCALE;
        shift[id] = beta[id] + (bias[id] - mean[id]) * s;
        return;
    }
    id -= N_LAYERS * HID;
    const int WT = 128 * 256 + 3 * 256 * 256;
    if (id < WT) {
        float v;
        if (id < 32768) {
            int n = id >> 7, k = id & 127;
            v = W0[k * 256 + n];
        } else {
            int t = id - 32768;
            int l = t >> 16;
            int r = t & 65535;
            int n = r >> 8, k = r & 255;
            v = Ws[l * 65536 + k * 256 + n];
        }
        v *= WSCALE;
        _Float16 h = (_Float16)v;
        Wh[id] = h;
        Wl[id] = (_Float16)(v - (float)h);
        return;
    }
    id -= WT;
    const int total4 = N_NODES * IN_DIM / 4;
    if (id < total4) {
        float4 v = ((const float4*)x)[id];
        int n = id >> 5;
        int c0 = (id & 31) * 4;
        f16x4 o;
        o.x = (_Float16)v.x; o.y = (_Float16)v.y; o.z = (_Float16)v.z; o.w = (_Float16)v.w;
        *(f16x4*)(X16 + (size_t)(c0 >> 5) * (N_NODES * 32) + (size_t)n * 32 + (c0 & 31)) = o;
    }
}

// ---------------- MFMA fp16 2-term GEMM + fused BN/ReLU epilogue (fp16 out) ----------------
__global__ __launch_bounds__(256) void k_gemm(const _Float16* __restrict__ A,
                                              const _Float16* __restrict__ Wh,
                                              const _Float16* __restrict__ Wl,
                                              const float* __restrict__ bnscale,
                                              const float* __restrict__ bnshift,
                                              _Float16* __restrict__ X16, int K) {
    __shared__ _Float16 sm[3 * 128 * 32]; // 24 KB: A | Wh | Wl tiles
    _Float16* tA  = sm;
    _Float16* tWh = sm + 4096;
    _Float16* tWl = sm + 8192;

    int tid = threadIdx.x;
    int lane = tid & 63;
    int w = tid >> 6;
    int wrow = w & 1, wcol = w >> 1;
    int row0 = blockIdx.x * 128;
    int col0 = blockIdx.y * 128;

    int srow = lane >> 2;
    int sch = lane & 3;

    f32x4 acc[4][4] = {};
    int m = lane & 15, q = lane >> 4;

    for (int k0 = 0; k0 < K; k0 += 32) {
        #pragma unroll
        for (int ii = 0; ii < 6; ++ii) {
            int G = w * 6 + ii;       // 0..23
            int mat = G >> 3;         // 0=A, 1=Wh, 2=Wl
            int grp = G & 7;
            const _Float16* gs = (mat == 0) ? A : (mat == 1) ? Wh : Wl;
            _Float16* ld = sm + mat * 4096;
            int rb = (mat == 0) ? row0 : col0;
            int rl = (mat == 0) ? N_NODES : (col0 + 128);
            int r = grp * 16 + srow;
            int grow = rb + r;
            int gch = sch ^ (r & 3);
            if (grow < rl)
                gl_lds16((const ushort_t*)(gs + (size_t)grow * K + k0 + gch * 8),
                         (ushort_t*)(ld + grp * 512));
        }
        __syncthreads();

        f16x8 af[4], whf[4], wlf[4];
        #pragma unroll
        for (int r = 0; r < 4; ++r) {
            int rr = wrow * 64 + r * 16 + m;
            int off = rr * 32 + ((q ^ (rr & 3)) << 3);
            af[r] = *(const f16x8*)(tA + off);
        }
        #pragma unroll
        for (int c = 0; c < 4; ++c) {
            int nn = wcol * 64 + c * 16 + m;
            int off = nn * 32 + ((q ^ (nn & 3)) << 3);
            whf[c] = *(const f16x8*)(tWh + off);
            wlf[c] = *(const f16x8*)(tWl + off);
        }
        #pragma unroll
        for (int r = 0; r < 4; ++r)
            #pragma unroll
            for (int c = 0; c < 4; ++c) {
                acc[r][c] = __builtin_amdgcn_mfma_f32_16x16x32_f16(af[r], whf[c], acc[r][c], 0, 0, 0);
                acc[r][c] = __builtin_amdgcn_mfma_f32_16x16x32_f16(af[r], wlf[c], acc[r][c], 0, 0, 0);
            }
        __syncthreads();
    }

    #pragma unroll
    for (int r = 0; r < 4; ++r) {
        int mrow = row0 + wrow * 64 + r * 16 + (lane >> 4) * 4;
        #pragma unroll
        for (int c = 0; c < 4; ++c) {
            int n = col0 + wcol * 64 + c * 16 + (lane & 15);
            float sc = bnscale[n];
            float sh = bnshift[n];
            f32x4 v = acc[r][c];
            _Float16* base = X16 + (size_t)(n >> 5) * (N_NODES * 32) + (n & 31);
            #pragma unroll
            for (int g = 0; g < 4; ++g)
                if (mrow + g < N_NODES)
                    base[(size_t)(mrow + g) * 32] =
                        (_Float16)fmaxf(fmaf(v[g], sc, sh), 0.f);
        }
    }
}

// ---------------- chunked gather on fp16 X: Âx -> fp16 A node-major ----------------
// ONE chunk per block (R8: 2 chunks = 6.4MB > 4MB per-XCD L2 -> FETCH 32->182MB,
// features fell out of L2. Working set must stay ~3.2MB). Slot-PAIRING for ILP +
// balance: each 4-lane quad owns slotA=k (ascending) and slotB=N-1-k (descending)
// -> two independent latency chains/thread, and degree-sorted pairing makes every
// quad's work ~2x avg (kills the makespan tail; replaces longest-first). Tail
// edges use zero-records: weight fp16(+0) -> fma no-op, src=0 reads valid memory.
// edata loads PLAIN (R1: nt/evict-first regressed).
#define GNB2 391  // ceil(25000/64) slot-pair blocks per chunk

__global__ __launch_bounds__(256) void k_gather(const _Float16* __restrict__ Xc,
                                                const int2* __restrict__ meta,
                                                const unsigned int* __restrict__ edata,
                                                const int* __restrict__ perm,
                                                const float* __restrict__ selfn,
                                                _Float16* __restrict__ A,
                                                int K, int cshift) {
    int bid = blockIdx.x;
    int chunk = bid & ((1 << cshift) - 1);
    int nb = bid >> cshift;
    const _Float16* Hc = Xc + (size_t)chunk * (N_NODES * 32);
    int slotA = nb * 64 + (threadIdx.x >> 2);
    if (slotA >= N_NODES / 2) return;
    int slotB = (N_NODES - 1) - slotA;
    int q8 = (threadIdx.x & 3) * 8;

    int nodeA = perm[slotA];
    int nodeB = perm[slotB];
    int2 mA = meta[slotA];
    int2 mB = meta[slotB];
    int strideA = mA.y & 0xFFFFF, degA = mA.y >> 20;
    int strideB = mB.y & 0xFFFFF, degB = mB.y >> 20;
    const unsigned int* epA = edata + mA.x;
    const unsigned int* epB = edata + mB.x;
    float snA = selfn[nodeA], snB = selfn[nodeB];

    float accA[8], accB[8];
    {
        f16x8 hA = *(const f16x8*)(Hc + (size_t)nodeA * 32 + q8);
        f16x8 hB = *(const f16x8*)(Hc + (size_t)nodeB * 32 + q8);
        #pragma unroll
        for (int i = 0; i < 8; ++i) {
            accA[i] = (float)hA[i] * snA;
            accB[i] = (float)hB[i] * snB;
        }
    }

    int degM = max(degA, degB);
    for (int j = 0; j < degM; j += 4) {
        unsigned int eA[4], eB[4];
        #pragma unroll
        for (int i = 0; i < 4; ++i) {
            eA[i] = (j + i < degA) ? epA[(size_t)(j + i) * strideA] : 0u;
            eB[i] = (j + i < degB) ? epB[(size_t)(j + i) * strideB] : 0u;
        }
        f16x8 aA[4], aB[4];
        #pragma unroll
        for (int i = 0; i < 4; ++i) {
            aA[i] = *(const f16x8*)(Hc + (size_t)(eA[i] & 0xFFFFu) * 32 + q8);
            aB[i] = *(const f16x8*)(Hc + (size_t)(eB[i] & 0xFFFFu) * 32 + q8);
        }
        #pragma unroll
        for (int i = 0; i < 4; ++i) {
            float wA = (float)__builtin_bit_cast(_Float16, (unsigned short)(eA[i] >> 16));
            float wB = (float)__builtin_bit_cast(_Float16, (unsigned short)(eB[i] >> 16));
            #pragma unroll
            for (int c = 0; c < 8; ++c) {
                accA[c] = fmaf((float)aA[i][c], wA, accA[c]);
                accB[c] = fmaf((float)aB[i][c], wB, accB[c]);
            }
        }
    }

    f16x8 oA, oB;
    #pragma unroll
    for (int i = 0; i < 8; ++i) { oA[i] = (_Float16)accA[i]; oB[i] = (_Float16)accB[i]; }
    __builtin_nontemporal_store(*(u32x4*)&oA,
        (u32x4*)(A + (size_t)nodeA * K + chunk * 32 + q8));
    __builtin_nontemporal_store(*(u32x4*)&oB,
        (u32x4*)(A + (size_t)nodeB * K + chunk * 32 + q8));
}

// ---------------- fused mean-pool + MLP head (one block per graph) ----------------
__global__ __launch_bounds__(128) void k_poolmlp(const _Float16* __restrict__ X16,
                                                 const int* __restrict__ gstart,
                                                 const int* __restrict__ gend,
                                                 const float* __restrict__ W1,
                                                 const float* __restrict__ b1,
                                                 const float* __restrict__ W2,
                                                 const float* __restrict__ b2,
                                                 float* __restrict__ out) {
    __shared__ float prow[HID];
    __shared__ float hred[2];
    int g = blockIdx.x;
    int s = gstart[g], e = gend[g];
    int j = threadIdx.x; // 0..127, channels j and j+128
    const _Float16* p0 = X16 + (size_t)(j >> 5) * (N_NODES * 32) + (j & 31);
    const _Float16* p1 = X16 + (size_t)((j >> 5) + 4) * (N_NODES * 32) + (j & 31);
    float a0 = 0.f, a1 = 0.f;
    for (int n = s; n < e; ++n) {
        a0 += (float)p0[(size_t)n * 32];
        a1 += (float)p1[(size_t)n * 32];
    }
    float inv = 1.0f / fmaxf((float)(e - s), 1.0f);
    prow[j] = a0 * inv;
    prow[j + 128] = a1 * inv;
    __syncthreads();
    float acc = 0.f;
    #pragma unroll 8
    for (int k = 0; k < HID; ++k) acc += prow[k] * W1[k * 128 + j];
    float h = fmaxf(acc + b1[j], 0.f);
    float p = h * W2[j];
    #pragma unroll
    for (int off = 32; off > 0; off >>= 1) p += __shfl_down(p, off, 64);
    if ((j & 63) == 0) hred[j >> 6] = p;
    __syncthreads();
    if (j == 0) out[g] = hred[0] + hred[1] + b2[0];
}

extern "C" void kernel_launch(void* const* d_in, const int* in_sizes, int n_in,
                              void* d_out, int out_size, void* d_ws, size_t ws_size,
                              hipStream_t stream) {
    const float* x      = (const float*)d_in[0];
    const int*   ei     = (const int*)d_in[1];
    const int*   batch  = (const int*)d_in[2];
    const float* convW0 = (const float*)d_in[3];
    const float* convWs = (const float*)d_in[4];
    const float* convB  = (const float*)d_in[5];
    const float* gamma  = (const float*)d_in[6];
    const float* beta   = (const float*)d_in[7];
    const float* mean   = (const float*)d_in[8];
    const float* var    = (const float*)d_in[9];
    const float* lin1W  = (const float*)d_in[10];
    const float* lin1b  = (const float*)d_in[11];
    const float* lin2W  = (const float*)d_in[12];
    const float* lin2b  = (const float*)d_in[13];
    float* out = (float*)d_out;

    const int* src = ei;
    const int* dst = ei + N_EDGES;

    const int WTOT = 128 * 256 + 3 * 256 * 256; // 229376

    char* wsb = (char*)d_ws;
    _Float16* x16a = (_Float16*)wsb;                     // N*HID fp16 (ping)
    _Float16* x16b = x16a + (size_t)N_NODES * HID;       // N*HID fp16 (pong)
    _Float16* Ab   = x16b + (size_t)N_NODES * HID;       // N*HID fp16 (GEMM A operand)
    _Float16* Wh16 = Ab + (size_t)N_NODES * HID;         // WTOT fp16
    _Float16* Wl16 = Wh16 + WTOT;                        // WTOT fp16
    float* dinv    = (float*)(Wl16 + WTOT);              // N
    float* selfn   = dinv + N_NODES;                     // N
    float* bnscale = selfn + N_NODES;                    // 4*HID
    float* bnshift = bnscale + N_LAYERS * HID;           // 4*HID
    // contiguous zero-init region: degi | bins | gstart | gend
    int*   degi    = (int*)(bnshift + N_LAYERS * HID);   // N
    int*   bins    = degi + N_NODES;                     // NBIN
    int*   gstart  = bins + NBIN;                        // G
    int*   gend    = gstart + N_GRAPHS;                  // G
    int*   binstart= gend + N_GRAPHS;                    // NBIN
    int*   bincur  = binstart + NBIN;                    // NBIN
    int*   edgebase= bincur + NBIN;                      // NBIN
    int*   cursor  = edgebase + NBIN;                    // N (node-indexed)
    int*   perm    = cursor + N_NODES;                   // N
    int2*  meta    = (int2*)(perm + N_NODES);            // N int2
    int4*  invmeta = (int4*)(meta + N_NODES);            // N int4 (per-node fill meta)
    unsigned int* edata = (unsigned int*)(invmeta + N_NODES); // E u32 (packed)

    hipMemsetAsync(degi, 0, (size_t)(N_NODES + NBIN + 2 * N_GRAPHS) * 4, stream);

    // CSR build + norms + degree sort (all parallel; closed-form offsets)
    k_degbounds<<<EDGE_BLKS + NODE_BLKS, 256, 0, stream>>>(dst, degi, batch, gstart, gend);
    k_nodeprep<<<NODE_BLKS, 256, 0, stream>>>(degi, dinv, selfn, bins, N_NODES);
    k_binscan<<<1, 64, 0, stream>>>(bins, binstart, bincur, edgebase);
    k_assign<<<NODE_BLKS, 256, 0, stream>>>(degi, binstart, edgebase, bins, bincur, dinv,
                                            perm, invmeta, meta, cursor, N_NODES);

    // fused: CSR fill (short-chain) + prep (streaming)
    const int PREP_TOT = N_LAYERS * HID + WTOT + N_NODES * IN_DIM / 4;
    const int PREP_BLKS = (PREP_TOT + 255) / 256;
    k_fillprep<<<EDGE_BLKS + PREP_BLKS, 256, 0, stream>>>(src, dst, dinv, invmeta,
                                                          cursor, edata,
                                                          gamma, beta, mean, var, convB,
                                                          convW0, convWs, x,
                                                          bnscale, bnshift, Wh16, Wl16, x16a);

    // layers: gather (Âx, fp16, slot-paired) -> fp16 2-term GEMM (+BN+ReLU, fp16 out)
    dim3 gg((N_NODES + 127) / 128, 2);
    _Float16* cur = x16a;
    for (int l = 0; l < N_LAYERS; ++l) {
        int K = (l == 0) ? IN_DIM : HID;
        int nchunk = K / 32;
        int cshift = (l == 0) ? 2 : 3;
        size_t woff = (l == 0) ? 0 : (size_t)(32768 + (l - 1) * 65536);
        k_gather<<<nchunk * GNB2, 256, 0, stream>>>(cur, meta, edata, perm, selfn,
                                                    Ab, K, cshift);
        _Float16* nxt = (cur == x16a) ? x16b : x16a;
        k_gemm<<<gg, 256, 0, stream>>>(Ab, Wh16 + woff, Wl16 + woff,
                                       bnscale + l * HID, bnshift + l * HID, nxt, K);
        cur = nxt;
    }

    k_poolmlp<<<N_GRAPHS, 128, 0, stream>>>(cur, gstart, gend, lin1W, lin1b, lin2W, lin2b, out);
}

// Round 10
// 449.176 us; speedup vs baseline: 1.1881x; 1.0588x over previous
//
#include <hip/hip_runtime.h>

#define N_NODES 50000
#define N_EDGES 800000
#define N_GRAPHS 2048
#define IN_DIM 128
#define HID 256
#define N_LAYERS 4
#define BN_EPS 1e-5f
#define NBIN 128
#define WSCALE 64.0f

#define EDGE_BLKS 3125   // ceil(800000/256)
#define NODE_BLKS 196    // ceil(50000/256)

typedef unsigned short ushort_t;
typedef float f32x4 __attribute__((ext_vector_type(4)));
typedef unsigned int u32x4 __attribute__((ext_vector_type(4)));
typedef _Float16 f16x8 __attribute__((ext_vector_type(8)));
typedef _Float16 f16x4 __attribute__((ext_vector_type(4)));

// ---- async global->LDS, 16B per lane ----
__device__ __forceinline__ void gl_lds16(const ushort_t* g, ushort_t* l) {
    __builtin_amdgcn_global_load_lds(
        (const __attribute__((address_space(1))) void*)g,
        (__attribute__((address_space(3))) void*)l, 16, 0, 0);
}

// ---------------- degree count + graph bounds (independent work, fused grid) ----------------
__global__ __launch_bounds__(256) void k_degbounds(const int* __restrict__ dst,
                                                   int* __restrict__ degi,
                                                   const int* __restrict__ batch,
                                                   int* __restrict__ gstart,
                                                   int* __restrict__ gend) {
    int bid = blockIdx.x;
    if (bid < EDGE_BLKS) {
        int e = bid * 256 + threadIdx.x;
        if (e < N_EDGES) atomicAdd(&degi[dst[e]], 1);
    } else {
        int n = (bid - EDGE_BLKS) * 256 + threadIdx.x;
        if (n >= N_NODES) return;
        int g = batch[n];
        if (n == 0 || batch[n - 1] != g) gstart[g] = n;
        if (n == N_NODES - 1 || batch[n + 1] != g) gend[g] = n + 1;
    }
}

// ---------------- node norms + degree histogram (fused, hierarchical) ----------------
__global__ __launch_bounds__(256) void k_nodeprep(const int* __restrict__ degi,
                                                  float* __restrict__ dinv,
                                                  float* __restrict__ selfn,
                                                  int* __restrict__ bins, int N) {
    __shared__ int lbin[NBIN];
    int t = threadIdx.x;
    if (t < NBIN) lbin[t] = 0;
    __syncthreads();
    int n = blockIdx.x * 256 + t;
    if (n < N) {
        int dg = degi[n];
        float d = 1.0f + (float)dg;
        dinv[n] = 1.0f / sqrtf(d);
        selfn[n] = 1.0f / d;
        atomicAdd(&lbin[min(dg, NBIN - 1)], 1);
    }
    __syncthreads();
    if (t < NBIN && lbin[t] > 0) atomicAdd(&bins[t], lbin[t]);
}

// ---------------- bin prefix (one wave, shfl scan over 128 bins) ----------------
__global__ void k_binscan(const int* __restrict__ bins, int* __restrict__ binstart,
                          int* __restrict__ bincur, int* __restrict__ edgebase) {
    int t = threadIdx.x & 63;
    int d0 = 2 * t, d1 = 2 * t + 1;
    int a = bins[d0], b = bins[d1];
    int ea = a * d0, eb = b * d1;
    int s = a + b, es = ea + eb;
    int ps = s, pe = es;
    #pragma unroll
    for (int off = 1; off < 64; off <<= 1) {
        int u = __shfl_up(ps, off, 64);
        int v = __shfl_up(pe, off, 64);
        if (t >= off) { ps += u; pe += v; }
    }
    int exs = ps - s, exe = pe - es;
    binstart[d0] = exs;     bincur[d0] = exs;     edgebase[d0] = exe;
    binstart[d1] = exs + a; bincur[d1] = exs + a; edgebase[d1] = exe + ea;
}

// ---------------- parallel slot assignment; emits per-slot meta + per-NODE fill meta ----------
// invmeta[n] = {edata_base, stride, bits(dinv[n]), 0}; cursor node-indexed (R7 win).
__global__ __launch_bounds__(256) void k_assign(const int* __restrict__ degi,
                                                const int* __restrict__ binstart,
                                                const int* __restrict__ edgebase,
                                                const int* __restrict__ bins,
                                                int* __restrict__ bincur,
                                                const float* __restrict__ dinv,
                                                int* __restrict__ perm,
                                                int4* __restrict__ invmeta,
                                                int2* __restrict__ meta, int* __restrict__ cursor,
                                                int N) {
    __shared__ int lbin[NBIN];
    __shared__ int lbase[NBIN];
    int t = threadIdx.x;
    if (t < NBIN) lbin[t] = 0;
    __syncthreads();
    int n = blockIdx.x * 256 + t;
    int d = 0, lrank = 0;
    if (n < N) {
        d = min(degi[n], NBIN - 1);
        lrank = atomicAdd(&lbin[d], 1);
    }
    __syncthreads();
    if (t < NBIN && lbin[t] > 0) lbase[t] = atomicAdd(&bincur[t], lbin[t]);
    __syncthreads();
    if (n < N) {
        int slot = lbase[d] + lrank;
        int base = edgebase[d] + (slot - binstart[d]);
        perm[slot] = n;
        int2 m;
        m.x = base;
        m.y = bins[d] | (d << 20);
        meta[slot] = m;
        int4 im;
        im.x = base;
        im.y = bins[d];
        im.z = __float_as_int(dinv[n]);
        im.w = 0;
        invmeta[n] = im;
        cursor[n] = 0;
    }
}

// ---------------- fused: CSR fill (short-chain scatter) + prep (streaming) ----------------
// Fill at its scatter floor (R6: partitioning loses; R7: chain 4->3 got 50->46us).
// Single-term fp16 weights (R10): Wl residual dropped — absmax was pinned at the
// fp16 OUTPUT quantum (2^-12), so the 2-term path was below output rounding anyway.
// record = (fp16(dinv[s]*dinv[d]) << 16) | src   (src < 65536 fits 16 bits)
__global__ __launch_bounds__(256) void k_fillprep(const int* __restrict__ src,
                                                  const int* __restrict__ dst,
                                                  const float* __restrict__ dinv,
                                                  const int4* __restrict__ invmeta,
                                                  int* __restrict__ cursor,
                                                  unsigned int* __restrict__ edata,
                                                  const float* __restrict__ gamma,
                                                  const float* __restrict__ beta,
                                                  const float* __restrict__ mean,
                                                  const float* __restrict__ var,
                                                  const float* __restrict__ bias,
                                                  const float* __restrict__ W0,
                                                  const float* __restrict__ Ws,
                                                  const float* __restrict__ x,
                                                  float* __restrict__ scale,
                                                  float* __restrict__ shift,
                                                  _Float16* __restrict__ Wh,
                                                  _Float16* __restrict__ X16) {
    int bid = blockIdx.x;
    if (bid < EDGE_BLKS) {
        int e = bid * 256 + threadIdx.x;
        if (e >= N_EDGES) return;
        int s = src[e], d = dst[e];
        int4 im = invmeta[d];               // base | stride | dinv[d]
        int j = atomicAdd(&cursor[d], 1);   // depends only on dst
        float wdd = __int_as_float(im.z);
        float wss = dinv[s];
        int pos = im.x + j * im.y;
        _Float16 hw = (_Float16)(wss * wdd);     // RTN
        edata[pos] = ((unsigned int)__builtin_bit_cast(unsigned short, hw) << 16) |
                     (unsigned int)s;
        return;
    }
    int id = (bid - EDGE_BLKS) * 256 + threadIdx.x;
    if (id < N_LAYERS * HID) {
        float s = gamma[id] * rsqrtf(var[id] + BN_EPS);
        scale[id] = s / WSCALE;
        shift[id] = beta[id] + (bias[id] - mean[id]) * s;
        return;
    }
    id -= N_LAYERS * HID;
    const int WT = 128 * 256 + 3 * 256 * 256;
    if (id < WT) {
        float v;
        if (id < 32768) {
            int n = id >> 7, k = id & 127;
            v = W0[k * 256 + n];
        } else {
            int t = id - 32768;
            int l = t >> 16;
            int r = t & 65535;
            int n = r >> 8, k = r & 255;
            v = Ws[l * 65536 + k * 256 + n];
        }
        Wh[id] = (_Float16)(v * WSCALE);
        return;
    }
    id -= WT;
    const int total4 = N_NODES * IN_DIM / 4;
    if (id < total4) {
        float4 v = ((const float4*)x)[id];
        int n = id >> 5;
        int c0 = (id & 31) * 4;
        f16x4 o;
        o.x = (_Float16)v.x; o.y = (_Float16)v.y; o.z = (_Float16)v.z; o.w = (_Float16)v.w;
        *(f16x4*)(X16 + (size_t)(c0 >> 5) * (N_NODES * 32) + (size_t)n * 32 + (c0 & 31)) = o;
    }
}

// ---------------- MFMA fp16 single-term GEMM + fused BN/ReLU epilogue (fp16 out) ----------
// R10: dropped the Wl residual term — halves MFMA work, staging (24->16 groups),
// and LDS (24->16KB). Weight precision now fp16 RTN (~5e-4 rel), same order as
// the fp16 A-operand rounding already present.
__global__ __launch_bounds__(256) void k_gemm(const _Float16* __restrict__ A,
                                              const _Float16* __restrict__ Wh,
                                              const float* __restrict__ bnscale,
                                              const float* __restrict__ bnshift,
                                              _Float16* __restrict__ X16, int K) {
    __shared__ _Float16 sm[2 * 128 * 32]; // 16 KB: A | Wh tiles
    _Float16* tA  = sm;
    _Float16* tWh = sm + 4096;

    int tid = threadIdx.x;
    int lane = tid & 63;
    int w = tid >> 6;
    int wrow = w & 1, wcol = w >> 1;
    int row0 = blockIdx.x * 128;
    int col0 = blockIdx.y * 128;

    int srow = lane >> 2;
    int sch = lane & 3;

    f32x4 acc[4][4] = {};
    int m = lane & 15, q = lane >> 4;

    for (int k0 = 0; k0 < K; k0 += 32) {
        #pragma unroll
        for (int ii = 0; ii < 4; ++ii) {
            int G = w * 4 + ii;       // 0..15
            int mat = G >> 3;         // 0=A, 1=Wh
            int grp = G & 7;
            const _Float16* gs = (mat == 0) ? A : Wh;
            _Float16* ld = sm + mat * 4096;
            int rb = (mat == 0) ? row0 : col0;
            int rl = (mat == 0) ? N_NODES : (col0 + 128);
            int r = grp * 16 + srow;
            int grow = rb + r;
            int gch = sch ^ (r & 3);
            if (grow < rl)
                gl_lds16((const ushort_t*)(gs + (size_t)grow * K + k0 + gch * 8),
                         (ushort_t*)(ld + grp * 512));
        }
        __syncthreads();

        f16x8 af[4], whf[4];
        #pragma unroll
        for (int r = 0; r < 4; ++r) {
            int rr = wrow * 64 + r * 16 + m;
            int off = rr * 32 + ((q ^ (rr & 3)) << 3);
            af[r] = *(const f16x8*)(tA + off);
        }
        #pragma unroll
        for (int c = 0; c < 4; ++c) {
            int nn = wcol * 64 + c * 16 + m;
            int off = nn * 32 + ((q ^ (nn & 3)) << 3);
            whf[c] = *(const f16x8*)(tWh + off);
        }
        #pragma unroll
        for (int r = 0; r < 4; ++r)
            #pragma unroll
            for (int c = 0; c < 4; ++c)
                acc[r][c] = __builtin_amdgcn_mfma_f32_16x16x32_f16(af[r], whf[c], acc[r][c], 0, 0, 0);
        __syncthreads();
    }

    #pragma unroll
    for (int r = 0; r < 4; ++r) {
        int mrow = row0 + wrow * 64 + r * 16 + (lane >> 4) * 4;
        #pragma unroll
        for (int c = 0; c < 4; ++c) {
            int n = col0 + wcol * 64 + c * 16 + (lane & 15);
            float sc = bnscale[n];
            float sh = bnshift[n];
            f32x4 v = acc[r][c];
            _Float16* base = X16 + (size_t)(n >> 5) * (N_NODES * 32) + (n & 31);
            #pragma unroll
            for (int g = 0; g < 4; ++g)
                if (mrow + g < N_NODES)
                    base[(size_t)(mrow + g) * 32] =
                        (_Float16)fmaxf(fmaf(v[g], sc, sh), 0.f);
        }
    }
}

// ---------------- chunked gather on fp16 X: Âx -> fp16 A node-major ----------------
// R7 form restored (proven best). ONE chunk/block (R8: 2 chunks blew per-XCD L2,
// FETCH 32->182MB). One slot per quad (R9: slot-pairing wasted issue on the light
// slot). 8-deep unroll; packed 4B records; edata loads PLAIN (R1); longest-first
// nb order (R4/R5 win).
#define GNB 782  // ceil(50000/64) slot-blocks per chunk

__global__ __launch_bounds__(256) void k_gather(const _Float16* __restrict__ Xc,
                                                const int2* __restrict__ meta,
                                                const unsigned int* __restrict__ edata,
                                                const int* __restrict__ perm,
                                                const float* __restrict__ selfn,
                                                _Float16* __restrict__ A,
                                                int K, int cshift) {
    int bid = blockIdx.x;
    int chunk = bid & ((1 << cshift) - 1);
    int nb = (GNB - 1) - (bid >> cshift);   // longest-work-first
    const _Float16* Hc = Xc + (size_t)chunk * (N_NODES * 32);
    int slot = nb * 64 + (threadIdx.x >> 2);
    if (slot >= N_NODES) return;
    int node = perm[slot];
    int2 m = meta[slot];
    int q8 = (threadIdx.x & 3) * 8;

    int stride = m.y & 0xFFFFF;
    int deg = m.y >> 20;
    const unsigned int* ep = edata + m.x;
    float sn = selfn[node];

    float acc[8];
    {
        f16x8 hv = *(const f16x8*)(Hc + (size_t)node * 32 + q8);
        #pragma unroll
        for (int i = 0; i < 8; ++i) acc[i] = (float)hv[i] * sn;
    }

    int j = 0;
    for (; j + 7 < deg; j += 8) {
        unsigned int e[8];
        #pragma unroll
        for (int i = 0; i < 8; ++i)
            e[i] = ep[(size_t)(j + i) * stride];
        f16x8 a[8];
        #pragma unroll
        for (int i = 0; i < 8; ++i)
            a[i] = *(const f16x8*)(Hc + (size_t)(e[i] & 0xFFFFu) * 32 + q8);
        #pragma unroll
        for (int i = 0; i < 8; ++i) {
            float w = (float)__builtin_bit_cast(_Float16, (unsigned short)(e[i] >> 16));
            #pragma unroll
            for (int c = 0; c < 8; ++c) acc[c] = fmaf((float)a[i][c], w, acc[c]);
        }
    }
    if (j + 3 < deg) {
        unsigned int e[4];
        #pragma unroll
        for (int i = 0; i < 4; ++i)
            e[i] = ep[(size_t)(j + i) * stride];
        f16x8 a[4];
        #pragma unroll
        for (int i = 0; i < 4; ++i)
            a[i] = *(const f16x8*)(Hc + (size_t)(e[i] & 0xFFFFu) * 32 + q8);
        #pragma unroll
        for (int i = 0; i < 4; ++i) {
            float w = (float)__builtin_bit_cast(_Float16, (unsigned short)(e[i] >> 16));
            #pragma unroll
            for (int c = 0; c < 8; ++c) acc[c] = fmaf((float)a[i][c], w, acc[c]);
        }
        j += 4;
    }
    for (; j < deg; ++j) {
        unsigned int e0 = ep[(size_t)j * stride];
        f16x8 a0 = *(const f16x8*)(Hc + (size_t)(e0 & 0xFFFFu) * 32 + q8);
        float w0 = (float)__builtin_bit_cast(_Float16, (unsigned short)(e0 >> 16));
        #pragma unroll
        for (int i = 0; i < 8; ++i) acc[i] = fmaf((float)a0[i], w0, acc[i]);
    }

    f16x8 o;
    #pragma unroll
    for (int i = 0; i < 8; ++i) o[i] = (_Float16)acc[i];
    u32x4 uv = *(u32x4*)&o;
    __builtin_nontemporal_store(uv, (u32x4*)(A + (size_t)node * K + chunk * 32 + q8));
}

// ---------------- fused mean-pool + MLP head (one block per graph) ----------------
__global__ __launch_bounds__(128) void k_poolmlp(const _Float16* __restrict__ X16,
                                                 const int* __restrict__ gstart,
                                                 const int* __restrict__ gend,
                                                 const float* __restrict__ W1,
                                                 const float* __restrict__ b1,
                                                 const float* __restrict__ W2,
                                                 const float* __restrict__ b2,
                                                 float* __restrict__ out) {
    __shared__ float prow[HID];
    __shared__ float hred[2];
    int g = blockIdx.x;
    int s = gstart[g], e = gend[g];
    int j = threadIdx.x; // 0..127, channels j and j+128
    const _Float16* p0 = X16 + (size_t)(j >> 5) * (N_NODES * 32) + (j & 31);
    const _Float16* p1 = X16 + (size_t)((j >> 5) + 4) * (N_NODES * 32) + (j & 31);
    float a0 = 0.f, a1 = 0.f;
    for (int n = s; n < e; ++n) {
        a0 += (float)p0[(size_t)n * 32];
        a1 += (float)p1[(size_t)n * 32];
    }
    float inv = 1.0f / fmaxf((float)(e - s), 1.0f);
    prow[j] = a0 * inv;
    prow[j + 128] = a1 * inv;
    __syncthreads();
    float acc = 0.f;
    #pragma unroll 8
    for (int k = 0; k < HID; ++k) acc += prow[k] * W1[k * 128 + j];
    float h = fmaxf(acc + b1[j], 0.f);
    float p = h * W2[j];
    #pragma unroll
    for (int off = 32; off > 0; off >>= 1) p += __shfl_down(p, off, 64);
    if ((j & 63) == 0) hred[j >> 6] = p;
    __syncthreads();
    if (j == 0) out[g] = hred[0] + hred[1] + b2[0];
}

extern "C" void kernel_launch(void* const* d_in, const int* in_sizes, int n_in,
                              void* d_out, int out_size, void* d_ws, size_t ws_size,
                              hipStream_t stream) {
    const float* x      = (const float*)d_in[0];
    const int*   ei     = (const int*)d_in[1];
    const int*   batch  = (const int*)d_in[2];
    const float* convW0 = (const float*)d_in[3];
    const float* convWs = (const float*)d_in[4];
    const float* convB  = (const float*)d_in[5];
    const float* gamma  = (const float*)d_in[6];
    const float* beta   = (const float*)d_in[7];
    const float* mean   = (const float*)d_in[8];
    const float* var    = (const float*)d_in[9];
    const float* lin1W  = (const float*)d_in[10];
    const float* lin1b  = (const float*)d_in[11];
    const float* lin2W  = (const float*)d_in[12];
    const float* lin2b  = (const float*)d_in[13];
    float* out = (float*)d_out;

    const int* src = ei;
    const int* dst = ei + N_EDGES;

    const int WTOT = 128 * 256 + 3 * 256 * 256; // 229376

    char* wsb = (char*)d_ws;
    _Float16* x16a = (_Float16*)wsb;                     // N*HID fp16 (ping)
    _Float16* x16b = x16a + (size_t)N_NODES * HID;       // N*HID fp16 (pong)
    _Float16* Ab   = x16b + (size_t)N_NODES * HID;       // N*HID fp16 (GEMM A operand)
    _Float16* Wh16 = Ab + (size_t)N_NODES * HID;         // WTOT fp16
    _Float16* Wl16 = Wh16 + WTOT;                        // WTOT fp16 (unused, kept for layout)
    float* dinv    = (float*)(Wl16 + WTOT);              // N
    float* selfn   = dinv + N_NODES;                     // N
    float* bnscale = selfn + N_NODES;                    // 4*HID
    float* bnshift = bnscale + N_LAYERS * HID;           // 4*HID
    // contiguous zero-init region: degi | bins | gstart | gend
    int*   degi    = (int*)(bnshift + N_LAYERS * HID);   // N
    int*   bins    = degi + N_NODES;                     // NBIN
    int*   gstart  = bins + NBIN;                        // G
    int*   gend    = gstart + N_GRAPHS;                  // G
    int*   binstart= gend + N_GRAPHS;                    // NBIN
    int*   bincur  = binstart + NBIN;                    // NBIN
    int*   edgebase= bincur + NBIN;                      // NBIN
    int*   cursor  = edgebase + NBIN;                    // N (node-indexed)
    int*   perm    = cursor + N_NODES;                   // N
    int2*  meta    = (int2*)(perm + N_NODES);            // N int2
    int4*  invmeta = (int4*)(meta + N_NODES);            // N int4 (per-node fill meta)
    unsigned int* edata = (unsigned int*)(invmeta + N_NODES); // E u32 (packed)

    hipMemsetAsync(degi, 0, (size_t)(N_NODES + NBIN + 2 * N_GRAPHS) * 4, stream);

    // CSR build + norms + degree sort (all parallel; closed-form offsets)
    k_degbounds<<<EDGE_BLKS + NODE_BLKS, 256, 0, stream>>>(dst, degi, batch, gstart, gend);
    k_nodeprep<<<NODE_BLKS, 256, 0, stream>>>(degi, dinv, selfn, bins, N_NODES);
    k_binscan<<<1, 64, 0, stream>>>(bins, binstart, bincur, edgebase);
    k_assign<<<NODE_BLKS, 256, 0, stream>>>(degi, binstart, edgebase, bins, bincur, dinv,
                                            perm, invmeta, meta, cursor, N_NODES);

    // fused: CSR fill (short-chain) + prep (streaming, single-term weights)
    const int PREP_TOT = N_LAYERS * HID + WTOT + N_NODES * IN_DIM / 4;
    const int PREP_BLKS = (PREP_TOT + 255) / 256;
    k_fillprep<<<EDGE_BLKS + PREP_BLKS, 256, 0, stream>>>(src, dst, dinv, invmeta,
                                                          cursor, edata,
                                                          gamma, beta, mean, var, convB,
                                                          convW0, convWs, x,
                                                          bnscale, bnshift, Wh16, x16a);

    // layers: gather (Âx, fp16) -> fp16 single-term GEMM (+BN+ReLU, fp16 out)
    dim3 gg((N_NODES + 127) / 128, 2);
    _Float16* cur = x16a;
    for (int l = 0; l < N_LAYERS; ++l) {
        int K = (l == 0) ? IN_DIM : HID;
        int nchunk = K / 32;
        int cshift = (l == 0) ? 2 : 3;
        size_t woff = (l == 0) ? 0 : (size_t)(32768 + (l - 1) * 65536);
        k_gather<<<nchunk * GNB, 256, 0, stream>>>(cur, meta, edata, perm, selfn,
                                                   Ab, K, cshift);
        _Float16* nxt = (cur == x16a) ? x16b : x16a;
        k_gemm<<<gg, 256, 0, stream>>>(Ab, Wh16 + woff,
                                       bnscale + l * HID, bnshift + l * HID, nxt, K);
        cur = nxt;
    }

    k_poolmlp<<<N_GRAPHS, 128, 0, stream>>>(cur, gstart, gend, lin1W, lin1b, lin2W, lin2b, out);
}

// Round 11
// 448.218 us; speedup vs baseline: 1.1907x; 1.0021x over previous
//
#include <hip/hip_runtime.h>

#define N_NODES 50000
#define N_EDGES 800000
#define N_GRAPHS 2048
#define IN_DIM 128
#define HID 256
#define N_LAYERS 4
#define BN_EPS 1e-5f
#define NBIN 128
#define WSCALE 64.0f

#define EDGE_BLKS 3125   // ceil(800000/256)
#define NODE_BLKS 196    // ceil(50000/256)

typedef unsigned short ushort_t;
typedef float f32x4 __attribute__((ext_vector_type(4)));
typedef unsigned int u32x4 __attribute__((ext_vector_type(4)));
typedef _Float16 f16x8 __attribute__((ext_vector_type(8)));
typedef _Float16 f16x4 __attribute__((ext_vector_type(4)));

// ---- async global->LDS, 16B per lane ----
__device__ __forceinline__ void gl_lds16(const ushort_t* g, ushort_t* l) {
    __builtin_amdgcn_global_load_lds(
        (const __attribute__((address_space(1))) void*)g,
        (__attribute__((address_space(3))) void*)l, 16, 0, 0);
}

// ---------------- degree count + graph bounds + prep (all independent; fused grid) ----------
// R11: prep moved here from under fill (R4: prep-under-fill cost ~4us net). degbounds
// is latency/atomic-bound with idle VALU — prep's streaming blocks backfill it, and
// prep's inputs (weights, x, bn params) are ready at launch.
__global__ __launch_bounds__(256) void k_degboundsprep(const int* __restrict__ dst,
                                                       int* __restrict__ degi,
                                                       const int* __restrict__ batch,
                                                       int* __restrict__ gstart,
                                                       int* __restrict__ gend,
                                                       const float* __restrict__ gamma,
                                                       const float* __restrict__ beta,
                                                       const float* __restrict__ mean,
                                                       const float* __restrict__ var,
                                                       const float* __restrict__ bias,
                                                       const float* __restrict__ W0,
                                                       const float* __restrict__ Ws,
                                                       const float* __restrict__ x,
                                                       float* __restrict__ scale,
                                                       float* __restrict__ shift,
                                                       _Float16* __restrict__ Wh,
                                                       _Float16* __restrict__ X16) {
    int bid = blockIdx.x;
    if (bid < EDGE_BLKS) {
        int e = bid * 256 + threadIdx.x;
        if (e < N_EDGES) atomicAdd(&degi[dst[e]], 1);
        return;
    }
    if (bid < EDGE_BLKS + NODE_BLKS) {
        int n = (bid - EDGE_BLKS) * 256 + threadIdx.x;
        if (n >= N_NODES) return;
        int g = batch[n];
        if (n == 0 || batch[n - 1] != g) gstart[g] = n;
        if (n == N_NODES - 1 || batch[n + 1] != g) gend[g] = n + 1;
        return;
    }
    int id = (bid - EDGE_BLKS - NODE_BLKS) * 256 + threadIdx.x;
    if (id < N_LAYERS * HID) {
        float s = gamma[id] * rsqrtf(var[id] + BN_EPS);
        scale[id] = s / WSCALE;
        shift[id] = beta[id] + (bias[id] - mean[id]) * s;
        return;
    }
    id -= N_LAYERS * HID;
    const int WT = 128 * 256 + 3 * 256 * 256;
    if (id < WT) {
        float v;
        if (id < 32768) {
            int n = id >> 7, k = id & 127;
            v = W0[k * 256 + n];
        } else {
            int t = id - 32768;
            int l = t >> 16;
            int r = t & 65535;
            int n = r >> 8, k = r & 255;
            v = Ws[l * 65536 + k * 256 + n];
        }
        Wh[id] = (_Float16)(v * WSCALE);
        return;
    }
    id -= WT;
    const int total4 = N_NODES * IN_DIM / 4;
    if (id < total4) {
        float4 v = ((const float4*)x)[id];
        int n = id >> 5;
        int c0 = (id & 31) * 4;
        f16x4 o;
        o.x = (_Float16)v.x; o.y = (_Float16)v.y; o.z = (_Float16)v.z; o.w = (_Float16)v.w;
        *(f16x4*)(X16 + (size_t)(c0 >> 5) * (N_NODES * 32) + (size_t)n * 32 + (c0 & 31)) = o;
    }
}

// ---------------- node norms + degree histogram (fused, hierarchical) ----------------
__global__ __launch_bounds__(256) void k_nodeprep(const int* __restrict__ degi,
                                                  float* __restrict__ dinv,
                                                  float* __restrict__ selfn,
                                                  int* __restrict__ bins, int N) {
    __shared__ int lbin[NBIN];
    int t = threadIdx.x;
    if (t < NBIN) lbin[t] = 0;
    __syncthreads();
    int n = blockIdx.x * 256 + t;
    if (n < N) {
        int dg = degi[n];
        float d = 1.0f + (float)dg;
        dinv[n] = 1.0f / sqrtf(d);
        selfn[n] = 1.0f / d;
        atomicAdd(&lbin[min(dg, NBIN - 1)], 1);
    }
    __syncthreads();
    if (t < NBIN && lbin[t] > 0) atomicAdd(&bins[t], lbin[t]);
}

// ---------------- bin prefix (one wave, shfl scan over 128 bins) ----------------
__global__ void k_binscan(const int* __restrict__ bins, int* __restrict__ binstart,
                          int* __restrict__ bincur, int* __restrict__ edgebase) {
    int t = threadIdx.x & 63;
    int d0 = 2 * t, d1 = 2 * t + 1;
    int a = bins[d0], b = bins[d1];
    int ea = a * d0, eb = b * d1;
    int s = a + b, es = ea + eb;
    int ps = s, pe = es;
    #pragma unroll
    for (int off = 1; off < 64; off <<= 1) {
        int u = __shfl_up(ps, off, 64);
        int v = __shfl_up(pe, off, 64);
        if (t >= off) { ps += u; pe += v; }
    }
    int exs = ps - s, exe = pe - es;
    binstart[d0] = exs;     bincur[d0] = exs;     edgebase[d0] = exe;
    binstart[d1] = exs + a; bincur[d1] = exs + a; edgebase[d1] = exe + ea;
}

// ---------------- parallel slot assignment; emits per-slot meta + per-NODE fill meta ----------
// invmeta[n] = {edata_base, stride, bits(dinv[n]), 0}; cursor node-indexed (R7 win).
__global__ __launch_bounds__(256) void k_assign(const int* __restrict__ degi,
                                                const int* __restrict__ binstart,
                                                const int* __restrict__ edgebase,
                                                const int* __restrict__ bins,
                                                int* __restrict__ bincur,
                                                const float* __restrict__ dinv,
                                                int* __restrict__ perm,
                                                int4* __restrict__ invmeta,
                                                int2* __restrict__ meta, int* __restrict__ cursor,
                                                int N) {
    __shared__ int lbin[NBIN];
    __shared__ int lbase[NBIN];
    int t = threadIdx.x;
    if (t < NBIN) lbin[t] = 0;
    __syncthreads();
    int n = blockIdx.x * 256 + t;
    int d = 0, lrank = 0;
    if (n < N) {
        d = min(degi[n], NBIN - 1);
        lrank = atomicAdd(&lbin[d], 1);
    }
    __syncthreads();
    if (t < NBIN && lbin[t] > 0) lbase[t] = atomicAdd(&bincur[t], lbin[t]);
    __syncthreads();
    if (n < N) {
        int slot = lbase[d] + lrank;
        int base = edgebase[d] + (slot - binstart[d]);
        perm[slot] = n;
        int2 m;
        m.x = base;
        m.y = bins[d] | (d << 20);
        meta[slot] = m;
        int4 im;
        im.x = base;
        im.y = bins[d];
        im.z = __float_as_int(dinv[n]);
        im.w = 0;
        invmeta[n] = im;
        cursor[n] = 0;
    }
}

// ---------------- CSR fill (short-chain scatter, standalone again) ----------------
// At its scatter floor (R6: partitioning loses; R7: chain 4->3 got 50->46us; R11:
// prep moved out). record = (fp16(dinv[s]*dinv[d]) << 16) | src
__global__ __launch_bounds__(256) void k_fill(const int* __restrict__ src,
                                              const int* __restrict__ dst,
                                              const float* __restrict__ dinv,
                                              const int4* __restrict__ invmeta,
                                              int* __restrict__ cursor,
                                              unsigned int* __restrict__ edata) {
    int e = blockIdx.x * 256 + threadIdx.x;
    if (e >= N_EDGES) return;
    int s = src[e], d = dst[e];
    int4 im = invmeta[d];               // base | stride | dinv[d]
    int j = atomicAdd(&cursor[d], 1);   // depends only on dst
    float wdd = __int_as_float(im.z);
    float wss = dinv[s];
    int pos = im.x + j * im.y;
    _Float16 hw = (_Float16)(wss * wdd);     // RTN
    edata[pos] = ((unsigned int)__builtin_bit_cast(unsigned short, hw) << 16) |
                 (unsigned int)s;
}

// ---------------- MFMA fp16 single-term GEMM, BK=64 + fused BN/ReLU epilogue ----------
// R11: BK 32->64 — halves the per-K-step barrier+vmcnt-drain count (the dominant
// stall in shallow-K MFMA loops), 32 MFMA per phase. LDS 32KB. Group = 8 rows x
// 64 ch (1KB, 64 lanes x 16B); read swizzle c^(rr&7) on the 128B row -> 2-way
// bank aliasing (free). Operands loaded per-k-half to cap VGPR.
__global__ __launch_bounds__(256) void k_gemm(const _Float16* __restrict__ A,
                                              const _Float16* __restrict__ Wh,
                                              const float* __restrict__ bnscale,
                                              const float* __restrict__ bnshift,
                                              _Float16* __restrict__ X16, int K) {
    __shared__ _Float16 sm[2 * 128 * 64]; // 32 KB: A | Wh tiles (BK=64)
    _Float16* tA  = sm;
    _Float16* tWh = sm + 8192;

    int tid = threadIdx.x;
    int lane = tid & 63;
    int w = tid >> 6;
    int wrow = w & 1, wcol = w >> 1;
    int row0 = blockIdx.x * 128;
    int col0 = blockIdx.y * 128;

    int srow8 = lane >> 3;   // 8 rows per group
    int sch8 = lane & 7;     // 8 segments of 8 fp16 = 64 ch

    f32x4 acc[4][4] = {};
    int m = lane & 15, q = lane >> 4;

    for (int k0 = 0; k0 < K; k0 += 64) {
        #pragma unroll
        for (int ii = 0; ii < 8; ++ii) {
            int G = w * 8 + ii;       // 0..31
            int mat = G >> 4;         // 0=A, 1=Wh
            int grp = G & 15;
            const _Float16* gs = (mat == 0) ? A : Wh;
            _Float16* ld = sm + mat * 8192;
            int rb = (mat == 0) ? row0 : col0;
            int rl = (mat == 0) ? N_NODES : (col0 + 128);
            int r = grp * 8 + srow8;
            int grow = rb + r;
            int gch = sch8 ^ (r & 7);
            if (grow < rl)
                gl_lds16((const ushort_t*)(gs + (size_t)grow * K + k0 + gch * 8),
                         (ushort_t*)(ld + grp * 512));
        }
        __syncthreads();

        #pragma unroll
        for (int t = 0; t < 2; ++t) {
            f16x8 af[4], whf[4];
            #pragma unroll
            for (int r = 0; r < 4; ++r) {
                int rr = wrow * 64 + r * 16 + m;
                int c = t * 4 + q;
                af[r] = *(const f16x8*)(tA + rr * 64 + ((c ^ (rr & 7)) << 3));
            }
            #pragma unroll
            for (int fc = 0; fc < 4; ++fc) {
                int nn = wcol * 64 + fc * 16 + m;
                int c = t * 4 + q;
                whf[fc] = *(const f16x8*)(tWh + nn * 64 + ((c ^ (nn & 7)) << 3));
            }
            #pragma unroll
            for (int r = 0; r < 4; ++r)
                #pragma unroll
                for (int fc = 0; fc < 4; ++fc)
                    acc[r][fc] = __builtin_amdgcn_mfma_f32_16x16x32_f16(af[r], whf[fc], acc[r][fc], 0, 0, 0);
        }
        __syncthreads();
    }

    #pragma unroll
    for (int r = 0; r < 4; ++r) {
        int mrow = row0 + wrow * 64 + r * 16 + (lane >> 4) * 4;
        #pragma unroll
        for (int c = 0; c < 4; ++c) {
            int n = col0 + wcol * 64 + c * 16 + (lane & 15);
            float sc = bnscale[n];
            float sh = bnshift[n];
            f32x4 v = acc[r][c];
            _Float16* base = X16 + (size_t)(n >> 5) * (N_NODES * 32) + (n & 31);
            #pragma unroll
            for (int g = 0; g < 4; ++g)
                if (mrow + g < N_NODES)
                    base[(size_t)(mrow + g) * 32] =
                        (_Float16)fmaxf(fmaf(v[g], sc, sh), 0.f);
        }
    }
}

// ---------------- chunked gather on fp16 X: Âx -> fp16 A node-major ----------------
// R7 form (proven best). ONE chunk/block (R8: 2 chunks blew per-XCD L2). One slot
// per quad (R9: pairing wasted issue). 8-deep unroll; packed 4B records; edata
// loads PLAIN (R1); longest-first nb order (R4/R5 win).
#define GNB 782  // ceil(50000/64) slot-blocks per chunk

__global__ __launch_bounds__(256) void k_gather(const _Float16* __restrict__ Xc,
                                                const int2* __restrict__ meta,
                                                const unsigned int* __restrict__ edata,
                                                const int* __restrict__ perm,
                                                const float* __restrict__ selfn,
                                                _Float16* __restrict__ A,
                                                int K, int cshift) {
    int bid = blockIdx.x;
    int chunk = bid & ((1 << cshift) - 1);
    int nb = (GNB - 1) - (bid >> cshift);   // longest-work-first
    const _Float16* Hc = Xc + (size_t)chunk * (N_NODES * 32);
    int slot = nb * 64 + (threadIdx.x >> 2);
    if (slot >= N_NODES) return;
    int node = perm[slot];
    int2 m = meta[slot];
    int q8 = (threadIdx.x & 3) * 8;

    int stride = m.y & 0xFFFFF;
    int deg = m.y >> 20;
    const unsigned int* ep = edata + m.x;
    float sn = selfn[node];

    float acc[8];
    {
        f16x8 hv = *(const f16x8*)(Hc + (size_t)node * 32 + q8);
        #pragma unroll
        for (int i = 0; i < 8; ++i) acc[i] = (float)hv[i] * sn;
    }

    int j = 0;
    for (; j + 7 < deg; j += 8) {
        unsigned int e[8];
        #pragma unroll
        for (int i = 0; i < 8; ++i)
            e[i] = ep[(size_t)(j + i) * stride];
        f16x8 a[8];
        #pragma unroll
        for (int i = 0; i < 8; ++i)
            a[i] = *(const f16x8*)(Hc + (size_t)(e[i] & 0xFFFFu) * 32 + q8);
        #pragma unroll
        for (int i = 0; i < 8; ++i) {
            float w = (float)__builtin_bit_cast(_Float16, (unsigned short)(e[i] >> 16));
            #pragma unroll
            for (int c = 0; c < 8; ++c) acc[c] = fmaf((float)a[i][c], w, acc[c]);
        }
    }
    if (j + 3 < deg) {
        unsigned int e[4];
        #pragma unroll
        for (int i = 0; i < 4; ++i)
            e[i] = ep[(size_t)(j + i) * stride];
        f16x8 a[4];
        #pragma unroll
        for (int i = 0; i < 4; ++i)
            a[i] = *(const f16x8*)(Hc + (size_t)(e[i] & 0xFFFFu) * 32 + q8);
        #pragma unroll
        for (int i = 0; i < 4; ++i) {
            float w = (float)__builtin_bit_cast(_Float16, (unsigned short)(e[i] >> 16));
            #pragma unroll
            for (int c = 0; c < 8; ++c) acc[c] = fmaf((float)a[i][c], w, acc[c]);
        }
        j += 4;
    }
    for (; j < deg; ++j) {
        unsigned int e0 = ep[(size_t)j * stride];
        f16x8 a0 = *(const f16x8*)(Hc + (size_t)(e0 & 0xFFFFu) * 32 + q8);
        float w0 = (float)__builtin_bit_cast(_Float16, (unsigned short)(e0 >> 16));
        #pragma unroll
        for (int i = 0; i < 8; ++i) acc[i] = fmaf((float)a0[i], w0, acc[i]);
    }

    f16x8 o;
    #pragma unroll
    for (int i = 0; i < 8; ++i) o[i] = (_Float16)acc[i];
    u32x4 uv = *(u32x4*)&o;
    __builtin_nontemporal_store(uv, (u32x4*)(A + (size_t)node * K + chunk * 32 + q8));
}

// ---------------- fused mean-pool + MLP head (one block per graph) ----------------
__global__ __launch_bounds__(128) void k_poolmlp(const _Float16* __restrict__ X16,
                                                 const int* __restrict__ gstart,
                                                 const int* __restrict__ gend,
                                                 const float* __restrict__ W1,
                                                 const float* __restrict__ b1,
                                                 const float* __restrict__ W2,
                                                 const float* __restrict__ b2,
                                                 float* __restrict__ out) {
    __shared__ float prow[HID];
    __shared__ float hred[2];
    int g = blockIdx.x;
    int s = gstart[g], e = gend[g];
    int j = threadIdx.x; // 0..127, channels j and j+128
    const _Float16* p0 = X16 + (size_t)(j >> 5) * (N_NODES * 32) + (j & 31);
    const _Float16* p1 = X16 + (size_t)((j >> 5) + 4) * (N_NODES * 32) + (j & 31);
    float a0 = 0.f, a1 = 0.f;
    for (int n = s; n < e; ++n) {
        a0 += (float)p0[(size_t)n * 32];
        a1 += (float)p1[(size_t)n * 32];
    }
    float inv = 1.0f / fmaxf((float)(e - s), 1.0f);
    prow[j] = a0 * inv;
    prow[j + 128] = a1 * inv;
    __syncthreads();
    float acc = 0.f;
    #pragma unroll 8
    for (int k = 0; k < HID; ++k) acc += prow[k] * W1[k * 128 + j];
    float h = fmaxf(acc + b1[j], 0.f);
    float p = h * W2[j];
    #pragma unroll
    for (int off = 32; off > 0; off >>= 1) p += __shfl_down(p, off, 64);
    if ((j & 63) == 0) hred[j >> 6] = p;
    __syncthreads();
    if (j == 0) out[g] = hred[0] + hred[1] + b2[0];
}

extern "C" void kernel_launch(void* const* d_in, const int* in_sizes, int n_in,
                              void* d_out, int out_size, void* d_ws, size_t ws_size,
                              hipStream_t stream) {
    const float* x      = (const float*)d_in[0];
    const int*   ei     = (const int*)d_in[1];
    const int*   batch  = (const int*)d_in[2];
    const float* convW0 = (const float*)d_in[3];
    const float* convWs = (const float*)d_in[4];
    const float* convB  = (const float*)d_in[5];
    const float* gamma  = (const float*)d_in[6];
    const float* beta   = (const float*)d_in[7];
    const float* mean   = (const float*)d_in[8];
    const float* var    = (const float*)d_in[9];
    const float* lin1W  = (const float*)d_in[10];
    const float* lin1b  = (const float*)d_in[11];
    const float* lin2W  = (const float*)d_in[12];
    const float* lin2b  = (const float*)d_in[13];
    float* out = (float*)d_out;

    const int* src = ei;
    const int* dst = ei + N_EDGES;

    const int WTOT = 128 * 256 + 3 * 256 * 256; // 229376

    char* wsb = (char*)d_ws;
    _Float16* x16a = (_Float16*)wsb;                     // N*HID fp16 (ping)
    _Float16* x16b = x16a + (size_t)N_NODES * HID;       // N*HID fp16 (pong)
    _Float16* Ab   = x16b + (size_t)N_NODES * HID;       // N*HID fp16 (GEMM A operand)
    _Float16* Wh16 = Ab + (size_t)N_NODES * HID;         // WTOT fp16
    _Float16* Wl16 = Wh16 + WTOT;                        // WTOT fp16 (unused, kept for layout)
    float* dinv    = (float*)(Wl16 + WTOT);              // N
    float* selfn   = dinv + N_NODES;                     // N
    float* bnscale = selfn + N_NODES;                    // 4*HID
    float* bnshift = bnscale + N_LAYERS * HID;           // 4*HID
    // contiguous zero-init region: degi | bins | gstart | gend
    int*   degi    = (int*)(bnshift + N_LAYERS * HID);   // N
    int*   bins    = degi + N_NODES;                     // NBIN
    int*   gstart  = bins + NBIN;                        // G
    int*   gend    = gstart + N_GRAPHS;                  // G
    int*   binstart= gend + N_GRAPHS;                    // NBIN
    int*   bincur  = binstart + NBIN;                    // NBIN
    int*   edgebase= bincur + NBIN;                      // NBIN
    int*   cursor  = edgebase + NBIN;                    // N (node-indexed)
    int*   perm    = cursor + N_NODES;                   // N
    int2*  meta    = (int2*)(perm + N_NODES);            // N int2
    int4*  invmeta = (int4*)(meta + N_NODES);            // N int4 (per-node fill meta)
    unsigned int* edata = (unsigned int*)(invmeta + N_NODES); // E u32 (packed)

    hipMemsetAsync(degi, 0, (size_t)(N_NODES + NBIN + 2 * N_GRAPHS) * 4, stream);

    // CSR build + norms + degree sort; prep fused under degbounds (R11)
    const int PREP_TOT = N_LAYERS * HID + WTOT + N_NODES * IN_DIM / 4;
    const int PREP_BLKS = (PREP_TOT + 255) / 256;
    k_degboundsprep<<<EDGE_BLKS + NODE_BLKS + PREP_BLKS, 256, 0, stream>>>(
        dst, degi, batch, gstart, gend,
        gamma, beta, mean, var, convB, convW0, convWs, x,
        bnscale, bnshift, Wh16, x16a);
    k_nodeprep<<<NODE_BLKS, 256, 0, stream>>>(degi, dinv, selfn, bins, N_NODES);
    k_binscan<<<1, 64, 0, stream>>>(bins, binstart, bincur, edgebase);
    k_assign<<<NODE_BLKS, 256, 0, stream>>>(degi, binstart, edgebase, bins, bincur, dinv,
                                            perm, invmeta, meta, cursor, N_NODES);

    // CSR fill (short-chain scatter, standalone)
    k_fill<<<EDGE_BLKS, 256, 0, stream>>>(src, dst, dinv, invmeta, cursor, edata);

    // layers: gather (Âx, fp16) -> fp16 single-term GEMM BK=64 (+BN+ReLU, fp16 out)
    dim3 gg((N_NODES + 127) / 128, 2);
    _Float16* cur = x16a;
    for (int l = 0; l < N_LAYERS; ++l) {
        int K = (l == 0) ? IN_DIM : HID;
        int nchunk = K / 32;
        int cshift = (l == 0) ? 2 : 3;
        size_t woff = (l == 0) ? 0 : (size_t)(32768 + (l - 1) * 65536);
        k_gather<<<nchunk * GNB, 256, 0, stream>>>(cur, meta, edata, perm, selfn,
                                                   Ab, K, cshift);
        _Float16* nxt = (cur == x16a) ? x16b : x16a;
        k_gemm<<<gg, 256, 0, stream>>>(Ab, Wh16 + woff,
                                       bnscale + l * HID, bnshift + l * HID, nxt, K);
        cur = nxt;
    }

    k_poolmlp<<<N_GRAPHS, 128, 0, stream>>>(cur, gstart, gend, lin1W, lin1b, lin2W, lin2b, out);
}